// Round 3
// baseline (321.521 us; speedup 1.0000x reference)
//
#include <hip/hip_runtime.h>
#include <hip/hip_bf16.h>
#include <stdint.h>

typedef __bf16 bf16_t;
typedef bf16_t bf16x8 __attribute__((ext_vector_type(8)));
typedef float  f32x4  __attribute__((ext_vector_type(4)));

#define M_TOK 2048
#define N_OUT 11008
#define K_IN  4096

#define GLDS16(gptr, lptr)                                                     \
    __builtin_amdgcn_global_load_lds(                                          \
        (__attribute__((address_space(1))) void*)(gptr),                       \
        (__attribute__((address_space(3))) void*)(lptr), 16, 0, 0)

// ---------------- pre-pass 1: dequant W int32 -> bf16 ----------------
__global__ __launch_bounds__(256)
void dequant_w(const int* __restrict__ Q, const float* __restrict__ S,
               const float* __restrict__ Z, bf16_t* __restrict__ W)
{
    const size_t total8 = (size_t)N_OUT * K_IN / 8;
    const size_t stride = (size_t)gridDim.x * blockDim.x;
    for (size_t i = (size_t)blockIdx.x * blockDim.x + threadIdx.x; i < total8; i += stride) {
        const size_t e0 = i * 8;
        const int row = (int)(e0 >> 12);
        const float s  = S[row];
        const float zs = Z[row] * s;
        const int4* q4 = (const int4*)(Q + e0);
        const int4 qa = q4[0], qb = q4[1];
        bf16x8 w;
        w[0] = (bf16_t)((float)qa.x * s - zs);
        w[1] = (bf16_t)((float)qa.y * s - zs);
        w[2] = (bf16_t)((float)qa.z * s - zs);
        w[3] = (bf16_t)((float)qa.w * s - zs);
        w[4] = (bf16_t)((float)qb.x * s - zs);
        w[5] = (bf16_t)((float)qb.y * s - zs);
        w[6] = (bf16_t)((float)qb.z * s - zs);
        w[7] = (bf16_t)((float)qb.w * s - zs);
        *(bf16x8*)(W + e0) = w;
    }
}

// ---------------- pre-pass 2: X f32 -> bf16 ----------------
__global__ __launch_bounds__(256)
void cvt_x(const float* __restrict__ X, bf16_t* __restrict__ Xb)
{
    const size_t total8 = (size_t)M_TOK * K_IN / 8;
    const size_t stride = (size_t)gridDim.x * blockDim.x;
    for (size_t i = (size_t)blockIdx.x * blockDim.x + threadIdx.x; i < total8; i += stride) {
        const size_t e0 = i * 8;
        const float4* x4 = (const float4*)(X + e0);
        const float4 xa = x4[0], xb = x4[1];
        bf16x8 v;
        v[0] = (bf16_t)xa.x; v[1] = (bf16_t)xa.y;
        v[2] = (bf16_t)xa.z; v[3] = (bf16_t)xa.w;
        v[4] = (bf16_t)xb.x; v[5] = (bf16_t)xb.y;
        v[6] = (bf16_t)xb.z; v[7] = (bf16_t)xb.w;
        *(bf16x8*)(Xb + e0) = v;
    }
}

// ---------------- main GEMM: 256x256 tile, BK=64, 8-phase schedule ----------------
// 8 waves = 2(M) x 4(N), interleaved wave tiling:
//   A row of frag m  = m*32 + wr*16 + fr   (mh=m>>2 selects A half-tile)
//   B row of frag n  = n*64 + wc*16 + fr   (nh=n>>1 selects B half-tile)
// LDS swizzle: 16B-chunk index c stored at c ^ (row&7); applied on the global
// SOURCE address (gload_lds writes linearly) and on the ds_read address.

#define ISSUE_A(BUF, KT, H) do {                                               \
    const bf16_t* s_ = gA + (size_t)((H) * 128) * K_IN + (KT) * 64;            \
    char* d_ = (char*)&sA[BUF][(H) * 128][0] + (wid << 10);                    \
    GLDS16(s_, d_);                                                            \
    GLDS16(s_ + (size_t)64 * K_IN, d_ + 8192);                                 \
} while (0)

#define ISSUE_B(BUF, KT, H) do {                                               \
    const bf16_t* s_ = gB + (size_t)((H) * 128) * K_IN + (KT) * 64;            \
    char* d_ = (char*)&sB[BUF][(H) * 128][0] + (wid << 10);                    \
    GLDS16(s_, d_);                                                            \
    GLDS16(s_ + (size_t)64 * K_IN, d_ + 8192);                                 \
} while (0)

#define VM(N) asm volatile("s_waitcnt vmcnt(" #N ")" ::: "memory")

#define PHASE(BUF, MH, NH, ISSUE, WAITOP) do {                                 \
    bf16x8 af[4][2]; bf16x8 bv[2][2];                                          \
    const char* Ab_ = (const char*)&sA[BUF][0][0];                             \
    const char* Bb_ = (const char*)&sB[BUF][0][0];                             \
    _Pragma("unroll")                                                          \
    for (int mq = 0; mq < 4; ++mq) {                                           \
        af[mq][0] = *(const bf16x8*)(Ab_ + ((MH)*4 + mq) * 4096 + rowA + ck0); \
        af[mq][1] = *(const bf16x8*)(Ab_ + ((MH)*4 + mq) * 4096 + rowA + ck1); \
    }                                                                          \
    _Pragma("unroll")                                                          \
    for (int nq = 0; nq < 2; ++nq) {                                           \
        bv[nq][0] = *(const bf16x8*)(Bb_ + ((NH)*2 + nq) * 8192 + rowB + ck0); \
        bv[nq][1] = *(const bf16x8*)(Bb_ + ((NH)*2 + nq) * 8192 + rowB + ck1); \
    }                                                                          \
    ISSUE;                                                                     \
    asm volatile("" ::: "memory");                                             \
    __builtin_amdgcn_s_barrier();                                              \
    asm volatile("s_waitcnt lgkmcnt(0)" ::: "memory");                         \
    __builtin_amdgcn_sched_barrier(0);                                         \
    __builtin_amdgcn_s_setprio(1);                                             \
    _Pragma("unroll")                                                          \
    for (int mq = 0; mq < 4; ++mq)                                             \
        _Pragma("unroll")                                                      \
        for (int nq = 0; nq < 2; ++nq) {                                       \
            acc[(MH)*4 + mq][(NH)*2 + nq] = __builtin_amdgcn_mfma_f32_16x16x32_bf16( \
                af[mq][0], bv[nq][0], acc[(MH)*4 + mq][(NH)*2 + nq], 0, 0, 0); \
            acc[(MH)*4 + mq][(NH)*2 + nq] = __builtin_amdgcn_mfma_f32_16x16x32_bf16( \
                af[mq][1], bv[nq][1], acc[(MH)*4 + mq][(NH)*2 + nq], 0, 0, 0); \
        }                                                                      \
    __builtin_amdgcn_s_setprio(0);                                             \
    WAITOP;                                                                    \
    asm volatile("" ::: "memory");                                             \
    __builtin_amdgcn_s_barrier();                                              \
    asm volatile("" ::: "memory");                                             \
} while (0)

__global__ __launch_bounds__(512, 2)
void gemm_8ph(const bf16_t* __restrict__ A,   // [M_TOK][K_IN] bf16
              const bf16_t* __restrict__ B,   // [N_OUT][K_IN] bf16 (B^T layout)
              const float* __restrict__ Bias,
              float* __restrict__ O)
{
    __shared__ bf16_t sA[2][256][64];   // 64 KB
    __shared__ bf16_t sB[2][256][64];   // 64 KB

    const int tid  = threadIdx.x;
    const int lane = tid & 63;
    const int wid  = tid >> 6;
    const int wr   = wid >> 2;   // 0..1
    const int wc   = wid & 3;    // 0..3
    const int fr   = lane & 15;
    const int fg   = lane >> 4;

    // XCD-aware swizzle: 344 blocks, 344%8==0 -> each XCD owns one M-row (43 blocks)
    const int bid = blockIdx.x;
    const int swz = (bid & 7) * 43 + (bid >> 3);
    const int bx  = swz % 43;           // N block
    const int by  = swz / 43;           // M block
    const long bm = (long)by * 256;
    const long bn = (long)bx * 256;

    // staging source (pre-swizzled chunk): thread t -> LDS slot row wid*8+(lane>>3),
    // chunk (lane&7); holds global chunk (lane&7)^(lane>>3)
    const int srow = (wid << 3) + (lane >> 3);
    const int scol = ((lane & 7) ^ (lane >> 3)) << 3;
    const bf16_t* gA = A + (size_t)(bm + srow) * K_IN + scol;
    const bf16_t* gB = B + (size_t)(bn + srow) * K_IN + scol;

    // ds_read addressing: logical (row rr, chunk cc) at byte rr*128 + ((cc^(rr&7))<<4)
    const int rowA = (wr * 16 + fr) * 128;
    const int rowB = (wc * 16 + fr) * 128;
    const int ck0  = (fg ^ (fr & 7)) << 4;   // ksub=0
    const int ck1  = ck0 ^ 64;               // ksub=1 (chunk bit2)

    f32x4 acc[8][4] = {};

    // prologue: stage tile0 fully + tile1 halves A0,B0 (matches steady-state order)
    ISSUE_A(0, 0, 0); ISSUE_B(0, 0, 0);
    ISSUE_A(0, 0, 1); ISSUE_B(0, 0, 1);
    ISSUE_A(1, 1, 0); ISSUE_B(1, 1, 0);
    VM(8);
    asm volatile("" ::: "memory");
    __builtin_amdgcn_s_barrier();
    asm volatile("" ::: "memory");

    // main loop: iteration computes K-tiles kt (buf0) and kt+1 (buf1)
    #pragma unroll 1
    for (int kt = 0; kt < 62; kt += 2) {
        PHASE(0, 0, 0, ISSUE_A(1, kt + 1, 1), VM(6));
        PHASE(0, 0, 1, ISSUE_B(1, kt + 1, 1), ((void)0));
        PHASE(0, 1, 0, ISSUE_A(0, kt + 2, 0), ((void)0));
        PHASE(0, 1, 1, ISSUE_B(0, kt + 2, 0), VM(8));
        PHASE(1, 0, 0, ISSUE_A(0, kt + 2, 1), VM(6));
        PHASE(1, 0, 1, ISSUE_B(0, kt + 2, 1), ((void)0));
        PHASE(1, 1, 0, ISSUE_A(1, kt + 3, 0), ((void)0));
        PHASE(1, 1, 1, ISSUE_B(1, kt + 3, 0), VM(8));
    }
    // last iteration (kt=62): no tile-64/65 issues; drain waits tightened
    PHASE(0, 0, 0, ISSUE_A(1, 63, 1), VM(6));
    PHASE(0, 0, 1, ISSUE_B(1, 63, 1), ((void)0));
    PHASE(0, 1, 0, ((void)0),          ((void)0));
    PHASE(0, 1, 1, ((void)0),          VM(4));
    PHASE(1, 0, 0, ((void)0),          VM(0));
    PHASE(1, 0, 1, ((void)0),          ((void)0));
    PHASE(1, 1, 0, ((void)0),          ((void)0));
    PHASE(1, 1, 1, ((void)0),          ((void)0));

    // epilogue: C row = bm + m*32 + wr*16 + fg*4 + r ; col = bn + n*64 + wc*16 + fr
    #pragma unroll
    for (int n = 0; n < 4; ++n) {
        const long col = bn + n * 64 + (wc << 4) + fr;
        const float bvadd = Bias[col];
        #pragma unroll
        for (int m = 0; m < 8; ++m) {
            const long row0 = bm + m * 32 + (wr << 4) + (fg << 2);
            #pragma unroll
            for (int r = 0; r < 4; ++r)
                O[(size_t)(row0 + r) * N_OUT + col] = acc[m][n][r] + bvadd;
        }
    }
}

// ---------------- fallback (fused) if ws too small ----------------
__global__ __launch_bounds__(256)
void qlinear_fused(const float* __restrict__ X,
                   const int*   __restrict__ Q,
                   const float* __restrict__ S,
                   const float* __restrict__ Z,
                   const float* __restrict__ Bias,
                   float* __restrict__ O)
{
    __shared__ bf16_t As[128][32];
    __shared__ bf16_t Bs[128][32];
    const int tid = threadIdx.x, lane = tid & 63, wid = tid >> 6;
    const int wr = wid >> 1, wc = wid & 1, fr = lane & 15, fg = lane >> 4;
    const int bm = blockIdx.y * 128, bn = blockIdx.x * 128;
    const int srow = tid >> 1, scol = (tid & 1) << 4;
    const float s_n = S[bn + srow];
    const float zs_n = Z[bn + srow] * s_n;
    const float* xptr = X + (size_t)(bm + srow) * K_IN + scol;
    const int*   qptr = Q + (size_t)(bn + srow) * K_IN + scol;
    f32x4 acc[4][4] = {};
    for (int k0 = 0; k0 < K_IN; k0 += 32) {
        float a[16]; int qi[16];
        { const float4* s4 = (const float4*)(xptr + k0);
          *(float4*)(a+0)=s4[0]; *(float4*)(a+4)=s4[1]; *(float4*)(a+8)=s4[2]; *(float4*)(a+12)=s4[3]; }
        { const int4* s4 = (const int4*)(qptr + k0);
          *(int4*)(qi+0)=s4[0]; *(int4*)(qi+4)=s4[1]; *(int4*)(qi+8)=s4[2]; *(int4*)(qi+12)=s4[3]; }
        float b[16];
        #pragma unroll
        for (int j = 0; j < 16; ++j) b[j] = (float)qi[j] * s_n - zs_n;
        bf16x8 pa0, pa1, pb0, pb1;
        #pragma unroll
        for (int j = 0; j < 8; ++j) {
            pa0[j]=(bf16_t)a[j]; pa1[j]=(bf16_t)a[j+8];
            pb0[j]=(bf16_t)b[j]; pb1[j]=(bf16_t)b[j+8];
        }
        *(bf16x8*)&As[srow][scol]   = pa0; *(bf16x8*)&As[srow][scol+8] = pa1;
        *(bf16x8*)&Bs[srow][scol]   = pb0; *(bf16x8*)&Bs[srow][scol+8] = pb1;
        __syncthreads();
        bf16x8 af[4], bfv[4];
        #pragma unroll
        for (int m = 0; m < 4; ++m) af[m] = *(const bf16x8*)&As[wr*64+m*16+fr][fg*8];
        #pragma unroll
        for (int n = 0; n < 4; ++n) bfv[n] = *(const bf16x8*)&Bs[wc*64+n*16+fr][fg*8];
        #pragma unroll
        for (int m = 0; m < 4; ++m)
            #pragma unroll
            for (int n = 0; n < 4; ++n)
                acc[m][n] = __builtin_amdgcn_mfma_f32_16x16x32_bf16(af[m], bfv[n], acc[m][n], 0,0,0);
        __syncthreads();
    }
    #pragma unroll
    for (int n = 0; n < 4; ++n) {
        const int col = bn + wc*64 + n*16 + fr;
        const float bv = Bias[col];
        #pragma unroll
        for (int m = 0; m < 4; ++m) {
            const int row0 = bm + wr*64 + m*16 + fg*4;
            #pragma unroll
            for (int r = 0; r < 4; ++r)
                O[(size_t)(row0 + r) * N_OUT + col] = acc[m][n][r] + bv;
        }
    }
}

extern "C" void kernel_launch(void* const* d_in, const int* in_sizes, int n_in,
                              void* d_out, int out_size, void* d_ws, size_t ws_size,
                              hipStream_t stream) {
    const float* X    = (const float*)d_in[0];
    const int*   Q    = (const int*)d_in[1];
    const float* S    = (const float*)d_in[2];
    const float* Z    = (const float*)d_in[3];
    const float* Bias = (const float*)d_in[4];
    float* O = (float*)d_out;

    const size_t wbytes = (size_t)N_OUT * K_IN * sizeof(bf16_t);
    const size_t xbytes = (size_t)M_TOK * K_IN * sizeof(bf16_t);

    if (ws_size >= wbytes + xbytes) {
        bf16_t* W  = (bf16_t*)d_ws;
        bf16_t* Xb = (bf16_t*)((char*)d_ws + wbytes);
        dequant_w<<<2048, 256, 0, stream>>>(Q, S, Z, W);
        cvt_x<<<1024, 256, 0, stream>>>(X, Xb);
        gemm_8ph<<<dim3(344), 512, 0, stream>>>(Xb, W, Bias, O);
    } else {
        dim3 grid(N_OUT / 128, M_TOK / 128);
        qlinear_fused<<<grid, 256, 0, stream>>>(X, Q, S, Z, Bias, O);
    }
}

// Round 4
// 205.555 us; speedup vs baseline: 1.5642x; 1.5642x over previous
//
#include <hip/hip_runtime.h>
#include <hip/hip_bf16.h>
#include <stdint.h>

typedef __bf16 bf16_t;
typedef bf16_t bf16x8 __attribute__((ext_vector_type(8)));
typedef float  f32x4  __attribute__((ext_vector_type(4)));
typedef int    i32x4  __attribute__((ext_vector_type(4)));

#define M_TOK 2048
#define N_OUT 11008
#define K_IN  4096

#define GLDS16(gptr, lptr)                                                     \
    __builtin_amdgcn_global_load_lds(                                          \
        (__attribute__((address_space(1))) void*)(gptr),                       \
        (__attribute__((address_space(3))) void*)(lptr), 16, 0, 0)

#define VM(N) asm volatile("s_waitcnt vmcnt(" #N ")" ::: "memory")
#define NOP ((void)0)

// ---------------- pre-pass 1: pack W int32 -> i8 (q-128), exact ----------------
__global__ __launch_bounds__(256)
void pack_w(const int* __restrict__ Q, signed char* __restrict__ W8)
{
    const size_t total16 = (size_t)N_OUT * K_IN / 16;
    const size_t stride  = (size_t)gridDim.x * blockDim.x;
    for (size_t i = (size_t)blockIdx.x * blockDim.x + threadIdx.x; i < total16; i += stride) {
        const size_t e0 = i * 16;
        const int4* q4 = (const int4*)(Q + e0);
        unsigned int pk[4];
        #pragma unroll
        for (int j = 0; j < 4; ++j) {
            const int4 q = q4[j];
            pk[j] =  (unsigned int)((q.x - 128) & 255)
                  | ((unsigned int)((q.y - 128) & 255) << 8)
                  | ((unsigned int)((q.z - 128) & 255) << 16)
                  | ((unsigned int)((q.w - 128) & 255) << 24);
        }
        *(int4*)(W8 + e0) = *(const int4*)pk;
    }
}

// ---------------- pre-pass 2: per-token symmetric i8 quant of X ----------------
__global__ __launch_bounds__(256)
void quant_x(const float* __restrict__ X, signed char* __restrict__ X8,
             float* __restrict__ dxv, float* __restrict__ sxv)
{
    const int row = blockIdx.x;
    const int tid = threadIdx.x;
    const float* xr = X + (size_t)row * K_IN + tid * 16;
    float v[16];
    #pragma unroll
    for (int j = 0; j < 4; ++j)
        *(float4*)(v + j * 4) = ((const float4*)xr)[j];

    float amax = 0.f;
    #pragma unroll
    for (int j = 0; j < 16; ++j) amax = fmaxf(amax, fabsf(v[j]));
    #pragma unroll
    for (int m = 1; m < 64; m <<= 1)
        amax = fmaxf(amax, __shfl_xor(amax, m));
    __shared__ float wmax[4];
    __shared__ int   wsum[4];
    const int wv = tid >> 6;
    if ((tid & 63) == 0) wmax[wv] = amax;
    __syncthreads();
    amax = fmaxf(fmaxf(wmax[0], wmax[1]), fmaxf(wmax[2], wmax[3]));
    amax = fmaxf(amax, 1e-20f);
    const float inv = 127.f / amax;

    int sum = 0;
    unsigned int pk[4];
    #pragma unroll
    for (int j = 0; j < 4; ++j) {
        unsigned int p = 0;
        #pragma unroll
        for (int i = 0; i < 4; ++i) {
            int xi = (int)__builtin_rintf(v[j * 4 + i] * inv);
            xi = max(-127, min(127, xi));
            sum += xi;
            p |= ((unsigned int)(xi & 255)) << (8 * i);
        }
        pk[j] = p;
    }
    *(int4*)(X8 + (size_t)row * K_IN + tid * 16) = *(const int4*)pk;

    #pragma unroll
    for (int m = 1; m < 64; m <<= 1) sum += __shfl_xor(sum, m);
    if ((tid & 63) == 0) wsum[wv] = sum;
    __syncthreads();
    if (tid == 0) {
        dxv[row] = amax * (1.f / 127.f);
        sxv[row] = (float)(wsum[0] + wsum[1] + wsum[2] + wsum[3]);
    }
}

// ---------------- main GEMM: i8, 128x256 tile, BK=64, 3-buf, 4-phase ----------
// 8 waves = 2(M-half) x 4(N-quarter); per wave 64x64 out = 4x4 tiles of 16x16.
// mfma_i32_16x16x64_i8: K-tile 64 in ONE k-step. acc = 64 VGPR/lane.
// LDS swizzle: 16B chunk c stored at c ^ ((row>>1)&3); applied on global source
// (gload_lds writes linearly) and on ds_read address (same involution).

#define ISSUE_A(SB, KT)  GLDS16(gA  + (KT) * 64, (char*)&sA[SB][0][0] + (tid << 4))
#define ISSUE_B0(SB, KT) GLDS16(gB0 + (KT) * 64, (char*)&sB[SB][0][0] + (tid << 4))
#define ISSUE_B1(SB, KT) GLDS16(gB1 + (KT) * 64, (char*)&sB[SB][0][0] + 8192 + (tid << 4))

#define PHASE_I8(BUF, MH, NH, ISSUE, WAITOP) do {                              \
    i32x4 af[2], bv[2];                                                        \
    const char* Ab_ = (const char*)&sA[BUF][0][0];                             \
    const char* Bb_ = (const char*)&sB[BUF][0][0];                             \
    _Pragma("unroll")                                                          \
    for (int mq = 0; mq < 2; ++mq)                                             \
        af[mq] = *(const i32x4*)(Ab_ + rowAoff + ((MH) * 2 + mq) * 1024 + ckA);\
    _Pragma("unroll")                                                          \
    for (int nq = 0; nq < 2; ++nq)                                             \
        bv[nq] = *(const i32x4*)(Bb_ + rowBoff + ((NH) * 2 + nq) * 1024 + ckA);\
    ISSUE;                                                                     \
    asm volatile("" ::: "memory");                                             \
    __builtin_amdgcn_s_barrier();                                              \
    asm volatile("s_waitcnt lgkmcnt(0)" ::: "memory");                         \
    __builtin_amdgcn_sched_barrier(0);                                         \
    __builtin_amdgcn_s_setprio(1);                                             \
    _Pragma("unroll")                                                          \
    for (int mq = 0; mq < 2; ++mq)                                             \
        _Pragma("unroll")                                                      \
        for (int nq = 0; nq < 2; ++nq)                                         \
            acc[(MH) * 2 + mq][(NH) * 2 + nq] =                                \
                __builtin_amdgcn_mfma_i32_16x16x64_i8(                         \
                    af[mq], bv[nq], acc[(MH) * 2 + mq][(NH) * 2 + nq], 0, 0, 0);\
    __builtin_amdgcn_s_setprio(0);                                             \
    WAITOP;                                                                    \
    asm volatile("" ::: "memory");                                             \
    __builtin_amdgcn_s_barrier();                                              \
} while (0)

#define TILE_FULL(BUF, STB, KT2) do {                                          \
    PHASE_I8(BUF, 0, 0, ISSUE_A(STB, KT2),  NOP);                              \
    PHASE_I8(BUF, 0, 1, ISSUE_B0(STB, KT2), NOP);                              \
    PHASE_I8(BUF, 1, 0, ISSUE_B1(STB, KT2), NOP);                              \
    PHASE_I8(BUF, 1, 1, NOP, VM(3));                                           \
} while (0)

#define TILE_DRAIN(BUF) do {                                                   \
    PHASE_I8(BUF, 0, 0, NOP, NOP);                                             \
    PHASE_I8(BUF, 0, 1, NOP, NOP);                                             \
    PHASE_I8(BUF, 1, 0, NOP, NOP);                                             \
    PHASE_I8(BUF, 1, 1, NOP, VM(0));                                           \
} while (0)

#define TILE_END(BUF) do {                                                     \
    PHASE_I8(BUF, 0, 0, NOP, NOP);                                             \
    PHASE_I8(BUF, 0, 1, NOP, NOP);                                             \
    PHASE_I8(BUF, 1, 0, NOP, NOP);                                             \
    PHASE_I8(BUF, 1, 1, NOP, NOP);                                             \
} while (0)

__global__ __launch_bounds__(512, 4)
void gemm_i8(const signed char* __restrict__ A8,   // [M_TOK][K_IN] i8
             const signed char* __restrict__ B8,   // [N_OUT][K_IN] i8
             const float* __restrict__ dxv,        // [M_TOK]
             const float* __restrict__ sxv,        // [M_TOK]
             const float* __restrict__ S,
             const float* __restrict__ Z,
             const float* __restrict__ Bias,
             float* __restrict__ O)
{
    __shared__ signed char sA[3][128][64];   // 24 KB
    __shared__ signed char sB[3][256][64];   // 48 KB  -> 72 KB total, 2 blocks/CU

    const int tid  = threadIdx.x;
    const int lane = tid & 63;
    const int wid  = tid >> 6;
    const int wr   = wid >> 2;   // 0..1  (M half)
    const int wc   = wid & 3;    // 0..3  (N quarter)
    const int fr   = lane & 15;
    const int fg   = lane >> 4;

    // XCD swizzle: 688 = 8 * 86; each XCD owns 2 consecutive M-rows (2*43 blocks)
    const int bid = blockIdx.x;
    const int swz = (bid & 7) * 86 + (bid >> 3);
    const int by  = swz / 43;
    const int bx  = swz - by * 43;
    const long bm = (long)by * 128;
    const long bn = (long)bx * 256;

    // staging: thread tid -> LDS chunk tid (row tid>>2, chunk tid&3); source
    // holds global chunk (tid&3) ^ ((row>>1)&3). Rows +128 keep same XOR.
    const int srow = tid >> 2;
    const int scg  = ((tid & 3) ^ ((srow >> 1) & 3)) << 4;
    const signed char* gA  = A8 + (size_t)(bm + srow) * K_IN + scg;
    const signed char* gB0 = B8 + (size_t)(bn + srow) * K_IN + scg;
    const signed char* gB1 = B8 + (size_t)(bn + 128 + srow) * K_IN + scg;

    // ds_read: logical (row, k-chunk fg) at byte row*64 + ((fg^((row>>1)&3))<<4)
    // (row>>1)&3 depends only on fr here (wr*64, wc*64, m*16 are 0 mod 8).
    const int ckA     = (fg ^ ((fr >> 1) & 3)) << 4;
    const int rowAoff = (wr * 64 + fr) * 64;
    const int rowBoff = (wc * 64 + fr) * 64;

    i32x4 acc[4][4] = {};

    // prologue: stage tiles 0,1 -> bufs 0,1
    ISSUE_A(0, 0); ISSUE_B0(0, 0); ISSUE_B1(0, 0);
    ISSUE_A(1, 1); ISSUE_B0(1, 1); ISSUE_B1(1, 1);
    VM(3);
    asm volatile("" ::: "memory");
    __builtin_amdgcn_s_barrier();

    #pragma unroll 1
    for (int t = 0; t < 60; t += 3) {
        TILE_FULL(0, 2, t + 2);
        TILE_FULL(1, 0, t + 3);
        TILE_FULL(2, 1, t + 4);
    }
    TILE_FULL(0, 2, 62);   // t=60
    TILE_FULL(1, 0, 63);   // t=61
    TILE_DRAIN(2);         // t=62
    TILE_END(0);           // t=63

    // epilogue: y = s*dx*(acc + (128-zp)*sx) + bias
    // C/D: col = lane&15, row = (lane>>4)*4 + reg (shape-determined, verified)
    float dxa[16], sxa[16];
    #pragma unroll
    for (int m = 0; m < 4; ++m)
        #pragma unroll
        for (int r = 0; r < 4; ++r) {
            const int row = (int)bm + wr * 64 + m * 16 + (fg << 2) + r;
            dxa[m * 4 + r] = dxv[row];
            sxa[m * 4 + r] = sxv[row];
        }
    #pragma unroll
    for (int n = 0; n < 4; ++n) {
        const long col = bn + wc * 64 + n * 16 + fr;
        const float s  = S[col];
        const float f  = 128.f - Z[col];
        const float bi = Bias[col];
        #pragma unroll
        for (int m = 0; m < 4; ++m) {
            const long row0 = bm + wr * 64 + m * 16 + (fg << 2);
            #pragma unroll
            for (int r = 0; r < 4; ++r) {
                const float g = (float)acc[m][n][r] + f * sxa[m * 4 + r];
                O[(size_t)(row0 + r) * N_OUT + col] = s * dxa[m * 4 + r] * g + bi;
            }
        }
    }
}

// ---------------- fallback (fused bf16) if ws too small ----------------
__global__ __launch_bounds__(256)
void qlinear_fused(const float* __restrict__ X,
                   const int*   __restrict__ Q,
                   const float* __restrict__ S,
                   const float* __restrict__ Z,
                   const float* __restrict__ Bias,
                   float* __restrict__ O)
{
    __shared__ bf16_t As[128][32];
    __shared__ bf16_t Bs[128][32];
    const int tid = threadIdx.x, lane = tid & 63, wid = tid >> 6;
    const int wr = wid >> 1, wc = wid & 1, fr = lane & 15, fg = lane >> 4;
    const int bm = blockIdx.y * 128, bn = blockIdx.x * 128;
    const int srow = tid >> 1, scol = (tid & 1) << 4;
    const float s_n = S[bn + srow];
    const float zs_n = Z[bn + srow] * s_n;
    const float* xptr = X + (size_t)(bm + srow) * K_IN + scol;
    const int*   qptr = Q + (size_t)(bn + srow) * K_IN + scol;
    f32x4 acc[4][4] = {};
    for (int k0 = 0; k0 < K_IN; k0 += 32) {
        float a[16]; int qi[16];
        { const float4* s4 = (const float4*)(xptr + k0);
          *(float4*)(a+0)=s4[0]; *(float4*)(a+4)=s4[1]; *(float4*)(a+8)=s4[2]; *(float4*)(a+12)=s4[3]; }
        { const int4* s4 = (const int4*)(qptr + k0);
          *(int4*)(qi+0)=s4[0]; *(int4*)(qi+4)=s4[1]; *(int4*)(qi+8)=s4[2]; *(int4*)(qi+12)=s4[3]; }
        float b[16];
        #pragma unroll
        for (int j = 0; j < 16; ++j) b[j] = (float)qi[j] * s_n - zs_n;
        bf16x8 pa0, pa1, pb0, pb1;
        #pragma unroll
        for (int j = 0; j < 8; ++j) {
            pa0[j]=(bf16_t)a[j]; pa1[j]=(bf16_t)a[j+8];
            pb0[j]=(bf16_t)b[j]; pb1[j]=(bf16_t)b[j+8];
        }
        *(bf16x8*)&As[srow][scol]   = pa0; *(bf16x8*)&As[srow][scol+8] = pa1;
        *(bf16x8*)&Bs[srow][scol]   = pb0; *(bf16x8*)&Bs[srow][scol+8] = pb1;
        __syncthreads();
        bf16x8 af[4], bfv[4];
        #pragma unroll
        for (int m = 0; m < 4; ++m) af[m] = *(const bf16x8*)&As[wr*64+m*16+fr][fg*8];
        #pragma unroll
        for (int n = 0; n < 4; ++n) bfv[n] = *(const bf16x8*)&Bs[wc*64+n*16+fr][fg*8];
        #pragma unroll
        for (int m = 0; m < 4; ++m)
            #pragma unroll
            for (int n = 0; n < 4; ++n)
                acc[m][n] = __builtin_amdgcn_mfma_f32_16x16x32_bf16(af[m], bfv[n], acc[m][n], 0,0,0);
        __syncthreads();
    }
    #pragma unroll
    for (int n = 0; n < 4; ++n) {
        const int col = bn + wc*64 + n*16 + fr;
        const float bv = Bias[col];
        #pragma unroll
        for (int m = 0; m < 4; ++m) {
            const int row0 = bm + wr*64 + m*16 + fg*4;
            #pragma unroll
            for (int r = 0; r < 4; ++r)
                O[(size_t)(row0 + r) * N_OUT + col] = acc[m][n][r] + bv;
        }
    }
}

extern "C" void kernel_launch(void* const* d_in, const int* in_sizes, int n_in,
                              void* d_out, int out_size, void* d_ws, size_t ws_size,
                              hipStream_t stream) {
    const float* X    = (const float*)d_in[0];
    const int*   Q    = (const int*)d_in[1];
    const float* S    = (const float*)d_in[2];
    const float* Z    = (const float*)d_in[3];
    const float* Bias = (const float*)d_in[4];
    float* O = (float*)d_out;

    const size_t wbytes = (size_t)N_OUT * K_IN;          // 45,088,768
    const size_t xbytes = (size_t)M_TOK * K_IN;          //  8,388,608
    const size_t need   = wbytes + xbytes + 4 * M_TOK * sizeof(float) + 64;

    if (ws_size >= need) {
        signed char* W8 = (signed char*)d_ws;
        signed char* X8 = (signed char*)d_ws + wbytes;
        float* dxv = (float*)((char*)d_ws + wbytes + xbytes);
        float* sxv = dxv + M_TOK;
        pack_w<<<2048, 256, 0, stream>>>(Q, W8);
        quant_x<<<M_TOK, 256, 0, stream>>>(X, X8, dxv, sxv);
        gemm_i8<<<dim3(688), 512, 0, stream>>>(X8, W8, dxv, sxv, S, Z, Bias, O);
    } else {
        dim3 grid(N_OUT / 128, M_TOK / 128);
        qlinear_fused<<<grid, 256, 0, stream>>>(X, Q, S, Z, Bias, O);
    }
}

// Round 5
// 182.115 us; speedup vs baseline: 1.7655x; 1.1287x over previous
//
#include <hip/hip_runtime.h>
#include <hip/hip_bf16.h>
#include <stdint.h>

typedef __bf16 bf16_t;
typedef bf16_t bf16x8 __attribute__((ext_vector_type(8)));
typedef float  f32x4  __attribute__((ext_vector_type(4)));
typedef int    i32x4  __attribute__((ext_vector_type(4)));

#define M_TOK 2048
#define N_OUT 11008
#define K_IN  4096

#define GLDS16(gptr, lptr)                                                     \
    __builtin_amdgcn_global_load_lds(                                          \
        (__attribute__((address_space(1))) void*)(gptr),                       \
        (__attribute__((address_space(3))) void*)(lptr), 16, 0, 0)

#define VM(N) asm volatile("s_waitcnt vmcnt(" #N ")" ::: "memory")
#define NOP ((void)0)

// ---------------- pre-pass 1: pack W int32 -> i8 (q-128), exact ----------------
__global__ __launch_bounds__(256)
void pack_w(const int* __restrict__ Q, signed char* __restrict__ W8)
{
    const size_t total16 = (size_t)N_OUT * K_IN / 16;
    const size_t stride  = (size_t)gridDim.x * blockDim.x;
    for (size_t i = (size_t)blockIdx.x * blockDim.x + threadIdx.x; i < total16; i += stride) {
        const size_t e0 = i * 16;
        const int4* q4 = (const int4*)(Q + e0);
        unsigned int pk[4];
        #pragma unroll
        for (int j = 0; j < 4; ++j) {
            const int4 q = q4[j];
            pk[j] =  (unsigned int)((q.x - 128) & 255)
                  | ((unsigned int)((q.y - 128) & 255) << 8)
                  | ((unsigned int)((q.z - 128) & 255) << 16)
                  | ((unsigned int)((q.w - 128) & 255) << 24);
        }
        *(int4*)(W8 + e0) = *(const int4*)pk;
    }
}

// ---------------- pre-pass 2: per-token symmetric i8 quant of X ----------------
__global__ __launch_bounds__(256)
void quant_x(const float* __restrict__ X, signed char* __restrict__ X8,
             float* __restrict__ dxv, float* __restrict__ sxv)
{
    const int row = blockIdx.x;
    const int tid = threadIdx.x;
    const float* xr = X + (size_t)row * K_IN + tid * 16;
    float v[16];
    #pragma unroll
    for (int j = 0; j < 4; ++j)
        *(float4*)(v + j * 4) = ((const float4*)xr)[j];

    float amax = 0.f;
    #pragma unroll
    for (int j = 0; j < 16; ++j) amax = fmaxf(amax, fabsf(v[j]));
    #pragma unroll
    for (int m = 1; m < 64; m <<= 1)
        amax = fmaxf(amax, __shfl_xor(amax, m));
    __shared__ float wmax[4];
    __shared__ int   wsum[4];
    const int wv = tid >> 6;
    if ((tid & 63) == 0) wmax[wv] = amax;
    __syncthreads();
    amax = fmaxf(fmaxf(wmax[0], wmax[1]), fmaxf(wmax[2], wmax[3]));
    amax = fmaxf(amax, 1e-20f);
    const float inv = 127.f / amax;

    int sum = 0;
    unsigned int pk[4];
    #pragma unroll
    for (int j = 0; j < 4; ++j) {
        unsigned int p = 0;
        #pragma unroll
        for (int i = 0; i < 4; ++i) {
            int xi = (int)__builtin_rintf(v[j * 4 + i] * inv);
            xi = max(-127, min(127, xi));
            sum += xi;
            p |= ((unsigned int)(xi & 255)) << (8 * i);
        }
        pk[j] = p;
    }
    *(int4*)(X8 + (size_t)row * K_IN + tid * 16) = *(const int4*)pk;

    #pragma unroll
    for (int m = 1; m < 64; m <<= 1) sum += __shfl_xor(sum, m);
    if ((tid & 63) == 0) wsum[wv] = sum;
    __syncthreads();
    if (tid == 0) {
        dxv[row] = amax * (1.f / 127.f);
        sxv[row] = (float)(wsum[0] + wsum[1] + wsum[2] + wsum[3]);
    }
}

// ---------------- main GEMM: i8, 128x256 tile, BK=64, 3-buf, 1 phase/K-tile ---
// 8 waves = 2(M-half) x 4(N-quarter); per wave 64x64 out = 4x4 tiles of 16x16.
// Per K-tile: read ALL 8 frags (4 A + 4 B), issue 3 stages, barrier, 16 MFMA.
// LDS swizzle: 16B chunk c stored at c ^ ((row>>1)&3), applied source-side
// (gload_lds writes linearly) and on ds_read address (same involution).

#define ISSUE_A(SB, KT)  GLDS16(gA  + (KT) * 64, (char*)&sA[SB][0][0] + (tid << 4))
#define ISSUE_B0(SB, KT) GLDS16(gB0 + (KT) * 64, (char*)&sB[SB][0][0] + (tid << 4))
#define ISSUE_B1(SB, KT) GLDS16(gB1 + (KT) * 64, (char*)&sB[SB][0][0] + 8192 + (tid << 4))

#define TILE_BODY(BUF, ISSUE, WAITOP) do {                                     \
    i32x4 af[4], bv[4];                                                        \
    const char* Ab_ = (const char*)&sA[BUF][0][0];                             \
    const char* Bb_ = (const char*)&sB[BUF][0][0];                             \
    _Pragma("unroll")                                                          \
    for (int mq = 0; mq < 4; ++mq)                                             \
        af[mq] = *(const i32x4*)(Ab_ + rowAoff + mq * 1024 + ckA);             \
    _Pragma("unroll")                                                          \
    for (int nq = 0; nq < 4; ++nq)                                             \
        bv[nq] = *(const i32x4*)(Bb_ + rowBoff + nq * 1024 + ckA);             \
    ISSUE;                                                                     \
    asm volatile("" ::: "memory");                                             \
    __builtin_amdgcn_s_barrier();                                              \
    asm volatile("s_waitcnt lgkmcnt(0)" ::: "memory");                         \
    __builtin_amdgcn_sched_barrier(0);                                         \
    __builtin_amdgcn_s_setprio(1);                                             \
    _Pragma("unroll")                                                          \
    for (int mq = 0; mq < 4; ++mq)                                             \
        _Pragma("unroll")                                                      \
        for (int nq = 0; nq < 4; ++nq)                                         \
            acc[mq][nq] = __builtin_amdgcn_mfma_i32_16x16x64_i8(               \
                af[mq], bv[nq], acc[mq][nq], 0, 0, 0);                         \
    __builtin_amdgcn_s_setprio(0);                                             \
    WAITOP;                                                                    \
    asm volatile("" ::: "memory");                                             \
    __builtin_amdgcn_s_barrier();                                              \
} while (0)

#define TILE_FULL(BUF, STB, KT2)                                               \
    TILE_BODY(BUF, { ISSUE_A(STB, KT2); ISSUE_B0(STB, KT2); ISSUE_B1(STB, KT2); }, VM(3))

#define TILE_DRAIN(BUF) TILE_BODY(BUF, NOP, VM(0))
#define TILE_END(BUF)   TILE_BODY(BUF, NOP, NOP)

__global__ __launch_bounds__(512, 4)
void gemm_i8(const signed char* __restrict__ A8,   // [M_TOK][K_IN] i8
             const signed char* __restrict__ B8,   // [N_OUT][K_IN] i8
             const float* __restrict__ dxv,        // [M_TOK]
             const float* __restrict__ sxv,        // [M_TOK]
             const float* __restrict__ S,
             const float* __restrict__ Z,
             const float* __restrict__ Bias,
             float* __restrict__ O)
{
    __shared__ signed char sA[3][128][64];   // 24 KB
    __shared__ signed char sB[3][256][64];   // 48 KB  -> 72 KB total, 2 blocks/CU

    const int tid  = threadIdx.x;
    const int lane = tid & 63;
    const int wid  = tid >> 6;
    const int wr   = wid >> 2;   // 0..1  (M half)
    const int wc   = wid & 3;    // 0..3  (N quarter)
    const int fr   = lane & 15;
    const int fg   = lane >> 4;

    // XCD swizzle: 688 = 8 * 86
    const int bid = blockIdx.x;
    const int swz = (bid & 7) * 86 + (bid >> 3);
    const int by  = swz / 43;
    const int bx  = swz - by * 43;
    const long bm = (long)by * 128;
    const long bn = (long)bx * 256;

    // staging: thread tid -> LDS chunk tid (row tid>>2, chunk tid&3); source
    // holds global chunk (tid&3) ^ ((row>>1)&3). Rows +128 keep same XOR.
    const int srow = tid >> 2;
    const int scg  = ((tid & 3) ^ ((srow >> 1) & 3)) << 4;
    const signed char* gA  = A8 + (size_t)(bm + srow) * K_IN + scg;
    const signed char* gB0 = B8 + (size_t)(bn + srow) * K_IN + scg;
    const signed char* gB1 = B8 + (size_t)(bn + 128 + srow) * K_IN + scg;

    // ds_read: logical (row, k-chunk fg) at byte row*64 + ((fg^((row>>1)&3))<<4)
    const int ckA     = (fg ^ ((fr >> 1) & 3)) << 4;
    const int rowAoff = (wr * 64 + fr) * 64;
    const int rowBoff = (wc * 64 + fr) * 64;

    i32x4 acc[4][4] = {};

    // prologue: stage tiles 0,1 -> bufs 0,1
    ISSUE_A(0, 0); ISSUE_B0(0, 0); ISSUE_B1(0, 0);
    ISSUE_A(1, 1); ISSUE_B0(1, 1); ISSUE_B1(1, 1);
    VM(3);
    asm volatile("" ::: "memory");
    __builtin_amdgcn_s_barrier();

    #pragma unroll 1
    for (int t = 0; t < 60; t += 3) {
        TILE_FULL(0, 2, t + 2);
        TILE_FULL(1, 0, t + 3);
        TILE_FULL(2, 1, t + 4);
    }
    TILE_FULL(0, 2, 62);   // t=60
    TILE_FULL(1, 0, 63);   // t=61
    TILE_DRAIN(2);         // t=62
    TILE_END(0);           // t=63

    // epilogue: y = s*dx*(acc + (128-zp)*sx) + bias
    // C/D: col = lane&15, row = (lane>>4)*4 + reg (shape-determined, verified)
    float dxa[16], sxa[16];
    #pragma unroll
    for (int m = 0; m < 4; ++m)
        #pragma unroll
        for (int r = 0; r < 4; ++r) {
            const int row = (int)bm + wr * 64 + m * 16 + (fg << 2) + r;
            dxa[m * 4 + r] = dxv[row];
            sxa[m * 4 + r] = sxv[row];
        }
    #pragma unroll
    for (int n = 0; n < 4; ++n) {
        const long col = bn + wc * 64 + n * 16 + fr;
        const float s  = S[col];
        const float f  = 128.f - Z[col];
        const float bi = Bias[col];
        #pragma unroll
        for (int m = 0; m < 4; ++m) {
            const long row0 = bm + wr * 64 + m * 16 + (fg << 2);
            #pragma unroll
            for (int r = 0; r < 4; ++r) {
                const float g = (float)acc[m][n][r] + f * sxa[m * 4 + r];
                O[(size_t)(row0 + r) * N_OUT + col] = s * dxa[m * 4 + r] * g + bi;
            }
        }
    }
}

// ---------------- fallback (fused bf16) if ws too small ----------------
__global__ __launch_bounds__(256)
void qlinear_fused(const float* __restrict__ X,
                   const int*   __restrict__ Q,
                   const float* __restrict__ S,
                   const float* __restrict__ Z,
                   const float* __restrict__ Bias,
                   float* __restrict__ O)
{
    __shared__ bf16_t As[128][32];
    __shared__ bf16_t Bs[128][32];
    const int tid = threadIdx.x, lane = tid & 63, wid = tid >> 6;
    const int wr = wid >> 1, wc = wid & 1, fr = lane & 15, fg = lane >> 4;
    const int bm = blockIdx.y * 128, bn = blockIdx.x * 128;
    const int srow = tid >> 1, scol = (tid & 1) << 4;
    const float s_n = S[bn + srow];
    const float zs_n = Z[bn + srow] * s_n;
    const float* xptr = X + (size_t)(bm + srow) * K_IN + scol;
    const int*   qptr = Q + (size_t)(bn + srow) * K_IN + scol;
    f32x4 acc[4][4] = {};
    for (int k0 = 0; k0 < K_IN; k0 += 32) {
        float a[16]; int qi[16];
        { const float4* s4 = (const float4*)(xptr + k0);
          *(float4*)(a+0)=s4[0]; *(float4*)(a+4)=s4[1]; *(float4*)(a+8)=s4[2]; *(float4*)(a+12)=s4[3]; }
        { const int4* s4 = (const int4*)(qptr + k0);
          *(int4*)(qi+0)=s4[0]; *(int4*)(qi+4)=s4[1]; *(int4*)(qi+8)=s4[2]; *(int4*)(qi+12)=s4[3]; }
        float b[16];
        #pragma unroll
        for (int j = 0; j < 16; ++j) b[j] = (float)qi[j] * s_n - zs_n;
        bf16x8 pa0, pa1, pb0, pb1;
        #pragma unroll
        for (int j = 0; j < 8; ++j) {
            pa0[j]=(bf16_t)a[j]; pa1[j]=(bf16_t)a[j+8];
            pb0[j]=(bf16_t)b[j]; pb1[j]=(bf16_t)b[j+8];
        }
        *(bf16x8*)&As[srow][scol]   = pa0; *(bf16x8*)&As[srow][scol+8] = pa1;
        *(bf16x8*)&Bs[srow][scol]   = pb0; *(bf16x8*)&Bs[srow][scol+8] = pb1;
        __syncthreads();
        bf16x8 af[4], bfv[4];
        #pragma unroll
        for (int m = 0; m < 4; ++m) af[m] = *(const bf16x8*)&As[wr*64+m*16+fr][fg*8];
        #pragma unroll
        for (int n = 0; n < 4; ++n) bfv[n] = *(const bf16x8*)&Bs[wc*64+n*16+fr][fg*8];
        #pragma unroll
        for (int m = 0; m < 4; ++m)
            #pragma unroll
            for (int n = 0; n < 4; ++n)
                acc[m][n] = __builtin_amdgcn_mfma_f32_16x16x32_bf16(af[m], bfv[n], acc[m][n], 0,0,0);
        __syncthreads();
    }
    #pragma unroll
    for (int n = 0; n < 4; ++n) {
        const int col = bn + wc*64 + n*16 + fr;
        const float bv = Bias[col];
        #pragma unroll
        for (int m = 0; m < 4; ++m) {
            const int row0 = bm + wr*64 + m*16 + fg*4;
            #pragma unroll
            for (int r = 0; r < 4; ++r)
                O[(size_t)(row0 + r) * N_OUT + col] = acc[m][n][r] + bv;
        }
    }
}

extern "C" void kernel_launch(void* const* d_in, const int* in_sizes, int n_in,
                              void* d_out, int out_size, void* d_ws, size_t ws_size,
                              hipStream_t stream) {
    const float* X    = (const float*)d_in[0];
    const int*   Q    = (const int*)d_in[1];
    const float* S    = (const float*)d_in[2];
    const float* Z    = (const float*)d_in[3];
    const float* Bias = (const float*)d_in[4];
    float* O = (float*)d_out;

    const size_t wbytes = (size_t)N_OUT * K_IN;          // 45,088,768
    const size_t xbytes = (size_t)M_TOK * K_IN;          //  8,388,608
    const size_t need   = wbytes + xbytes + 4 * M_TOK * sizeof(float) + 64;

    if (ws_size >= need) {
        signed char* W8 = (signed char*)d_ws;
        signed char* X8 = (signed char*)d_ws + wbytes;
        float* dxv = (float*)((char*)d_ws + wbytes + xbytes);
        float* sxv = dxv + M_TOK;
        pack_w<<<2048, 256, 0, stream>>>(Q, W8);
        quant_x<<<M_TOK, 256, 0, stream>>>(X, X8, dxv, sxv);
        gemm_i8<<<dim3(688), 512, 0, stream>>>(X8, W8, dxv, sxv, S, Z, Bias, O);
    } else {
        dim3 grid(N_OUT / 128, M_TOK / 128);
        qlinear_fused<<<grid, 256, 0, stream>>>(X, Q, S, Z, Bias, O);
    }
}